// Round 7
// baseline (1395.083 us; speedup 1.0000x reference)
//
#include <hip/hip_runtime.h>
#include <hip/hip_fp16.h>

typedef _Float16 f16;
typedef _Float16 f16x2 __attribute__((ext_vector_type(2)));
typedef _Float16 f16x4 __attribute__((ext_vector_type(4)));
typedef _Float16 f16x8 __attribute__((ext_vector_type(8)));
typedef float    f32x4 __attribute__((ext_vector_type(4)));

// Problem constants: B=64, S=32, P=49, F=2048, E=512, H=512, V=32000

// ---- LLC-coherent (cross-XCD) access helpers: relaxed agent-scope atomics ----
// Plain sc loads/stores through the LLC. NO fences, NO atomic RMW (R6 lesson:
// same-address far-atomic RMWs serialize ~100s of ns each -> 10+us/rendezvous).
static __device__ __forceinline__ unsigned ldau(const unsigned* p) {
  return __hip_atomic_load(p, __ATOMIC_RELAXED, __HIP_MEMORY_SCOPE_AGENT);
}
static __device__ __forceinline__ void stau(unsigned* p, unsigned v) {
  __hip_atomic_store(p, v, __ATOMIC_RELAXED, __HIP_MEMORY_SCOPE_AGENT);
}
static __device__ __forceinline__ float ldaf(const float* p) {
  return __hip_atomic_load(p, __ATOMIC_RELAXED, __HIP_MEMORY_SCOPE_AGENT);
}
static __device__ __forceinline__ void staf(float* p, float v) {
  __hip_atomic_store(p, v, __ATOMIC_RELAXED, __HIP_MEMORY_SCOPE_AGENT);
}

// ---------------- fused f32 -> f16 conversions (ONE dispatch for all weights) ----------------
__global__ __launch_bounds__(256) void k_prep(
    const float* __restrict__ feat, const float* __restrict__ W_a,
    const float* __restrict__ W_ih, const float* __restrict__ fc_W,
    const float* __restrict__ W_hh, const float* __restrict__ U_a,
    const float* __restrict__ Wh, const float* __restrict__ Wc,
    f16* __restrict__ feat_h, f16* __restrict__ W_a_h,
    f16* __restrict__ W_ih_h, f16* __restrict__ fc_W_h,
    f16* __restrict__ Wcat_h, f16* __restrict__ Whc_h) {
  const long c0 = 1605632;              // feat      (6422528 f32 /4)
  const long c1 = c0 + 262144;          // W_a       (1048576)
  const long c2 = c1 + 1310720;         // W_ih      (5242880)
  const long c3 = c2 + 4096000;         // fc_W      (16384000)
  const long c4 = c3 + 262144;          // W_hh -> Wcat rows 0..2047
  const long c5 = c4 + 65536;           // U_a  -> Wcat rows 2048..2559
  const long c6 = c5 + 262144;          // Wh   -> Whc rows 0..511
  const long c7 = c6 + 262144;          // Wc   -> Whc rows 512..1023
  long i = (long)blockIdx.x * 256 + threadIdx.x;
  const long stride = (long)gridDim.x * 256;
  for (; i < c7; i += stride) {
    const float4* s; f16x4* d; long j;
    if (i < c0)      { s = (const float4*)feat; d = (f16x4*)feat_h; j = i; }
    else if (i < c1) { s = (const float4*)W_a;  d = (f16x4*)W_a_h;  j = i - c0; }
    else if (i < c2) { s = (const float4*)W_ih; d = (f16x4*)W_ih_h; j = i - c1; }
    else if (i < c3) { s = (const float4*)fc_W; d = (f16x4*)fc_W_h; j = i - c2; }
    else if (i < c4) { s = (const float4*)W_hh; d = (f16x4*)Wcat_h; j = i - c3; }
    else if (i < c5) { s = (const float4*)U_a;  d = (f16x4*)(Wcat_h + 2048l * 512); j = i - c4; }
    else if (i < c6) { s = (const float4*)Wh;   d = (f16x4*)Whc_h;  j = i - c5; }
    else             { s = (const float4*)Wc;   d = (f16x4*)(Whc_h + 1048576l); j = i - c6; }
    float4 v = s[j];
    f16x4 o; o.x = (f16)v.x; o.y = (f16)v.y; o.z = (f16)v.z; o.w = (f16)v.w;
    d[j] = o;
  }
}

// ---------------- embedding gather -> f16 A matrix (n = b*32+s) ----------------
__global__ void k_embed(const int* __restrict__ caps, const float* __restrict__ table,
                        f16* __restrict__ out) {
  int n = blockIdx.x;                 // 0..2047
  int tok = caps[n];
  const float* src = table + (long)tok * 512;
  f16* dst = out + (long)n * 512;
  for (int e = threadIdx.x; e < 512; e += 256) dst[e] = (f16)src[e];
}

// ---------------- mean of features over P (from f16 feat) -> f16 [64,2048] ----------------
__global__ __launch_bounds__(256) void k_mean(const f16* __restrict__ feat_h,
                                              f16* __restrict__ mean_h) {
  int b = blockIdx.x;
  int e4 = blockIdx.y * 256 + threadIdx.x;      // f16x4 index within row: 0..511
  const f16x4* src = (const f16x4*)(feat_h + (long)b * 49 * 2048) + e4;
  float s0 = 0.f, s1 = 0.f, s2 = 0.f, s3 = 0.f;
#pragma unroll 7
  for (int p = 0; p < 49; ++p) {
    f16x4 v = src[p * 512];
    s0 += (float)v.x; s1 += (float)v.y; s2 += (float)v.z; s3 += (float)v.w;
  }
  const float inv = 1.f / 49.f;
  f16x4 o; o.x = (f16)(s0 * inv); o.y = (f16)(s1 * inv); o.z = (f16)(s2 * inv); o.w = (f16)(s3 * inv);
  ((f16x4*)(mean_h + (long)b * 2048))[e4] = o;
}

// ---------------- split h0/c0 GEMM result, add biases; pack h as f16x2-in-uint ----------------
__global__ __launch_bounds__(512) void k_h0split(const float* __restrict__ Rh0,
                                                 const float* __restrict__ bh,
                                                 const float* __restrict__ bc,
                                                 unsigned* __restrict__ h2,
                                                 float* __restrict__ c_state) {
  int b = blockIdx.x, j = threadIdx.x;
  float hv = Rh0[(long)b * 1024 + j] + bh[j];
  c_state[(long)b * 512 + j] = Rh0[(long)b * 1024 + 512 + j] + bc[j];
  unsigned hb = (unsigned)__builtin_bit_cast(unsigned short, (f16)hv);
  unsigned pr = __shfl_xor(hb, 1);
  if ((j & 1) == 0) h2[(long)b * 256 + (j >> 1)] = hb | (pr << 16);
}

// ---------------- generic f16 MFMA GEMM (64x64 tile): C = A @ W^T + bias ----------------
// 1-D grid, M-fastest mapping. mode 0: f32 out; mode 1: f16 out; mode 2: f16 g-interleaved
__global__ __launch_bounds__(256) void k_gemm(const f16* __restrict__ A, long lda,
                                              const f16* __restrict__ Bw, long ldb,
                                              const float* __restrict__ bias1,
                                              const float* __restrict__ bias2,
                                              void* __restrict__ Cout, long ldc,
                                              int K, int mode, int n_mtiles) {
  __shared__ f16 As[64][40];
  __shared__ f16 Bs[64][40];
  const int tid = threadIdx.x;
  const int lane = tid & 63, wave = tid >> 6;
  const int bid = blockIdx.x;
  const long m0 = (long)(bid % n_mtiles) * 64, n0 = (long)(bid / n_mtiles) * 64;
  const int lr = tid >> 2, lc = (tid & 3) * 8;
  const int wr = (wave >> 1) * 32, wc = (wave & 1) * 32;
  f32x4 acc[2][2] = {};
  const f16* Ap = A + (m0 + lr) * lda + lc;
  const f16* Bp = Bw + (n0 + lr) * ldb + lc;
  for (int k0 = 0; k0 < K; k0 += 32) {
    uint4 av = *(const uint4*)(Ap + k0);
    uint4 bv = *(const uint4*)(Bp + k0);
    __syncthreads();
    *(uint4*)&As[lr][lc] = av;
    *(uint4*)&Bs[lr][lc] = bv;
    __syncthreads();
#pragma unroll
    for (int mi = 0; mi < 2; ++mi) {
      f16x8 af = *(const f16x8*)&As[wr + mi * 16 + (lane & 15)][(lane >> 4) * 8];
#pragma unroll
      for (int ni = 0; ni < 2; ++ni) {
        f16x8 bf = *(const f16x8*)&Bs[wc + ni * 16 + (lane & 15)][(lane >> 4) * 8];
        acc[mi][ni] = __builtin_amdgcn_mfma_f32_16x16x32_f16(af, bf, acc[mi][ni], 0, 0, 0);
      }
    }
  }
#pragma unroll
  for (int mi = 0; mi < 2; ++mi)
#pragma unroll
    for (int ni = 0; ni < 2; ++ni) {
      int row_b = wr + mi * 16 + (lane >> 4) * 4;
      long gcol = n0 + wc + ni * 16 + (lane & 15);
      float badd = (bias1 ? bias1[gcol] : 0.f) + (bias2 ? bias2[gcol] : 0.f);
#pragma unroll
      for (int r = 0; r < 4; ++r) {
        long grow = m0 + row_b + r;
        float v = acc[mi][ni][r] + badd;
        if (mode == 0)      ((float*)Cout)[grow * ldc + gcol] = v;
        else if (mode == 1) ((f16*)Cout)[grow * ldc + gcol] = (f16)v;
        else                ((f16*)Cout)[grow * 2048 + ((gcol & 511) << 2) + (gcol >> 9)] = (f16)v;
      }
    }
}

// ---------------- 128x128-tile f16 MFMA GEMM: C[M,N] = A[M,K] @ W[N,K]^T + bias (f32 out) ---
// 512 threads / 8 waves. 1-D grid, M-fastest.
__global__ __launch_bounds__(512) void k_gemm128(const f16* __restrict__ A, long lda,
                                                 const f16* __restrict__ Bw, long ldb,
                                                 const float* __restrict__ bias1,
                                                 const float* __restrict__ bias2,
                                                 float* __restrict__ Cout, long ldc,
                                                 int K, int n_mtiles) {
  __shared__ f16 As[128][40];
  __shared__ f16 Bs[128][40];
  const int tid = threadIdx.x;
  const int lane = tid & 63, wave = tid >> 6;
  const int wm = wave & 3, wn = wave >> 2;
  const int bid = blockIdx.x;
  const long m0 = (long)(bid % n_mtiles) * 128, n0 = (long)(bid / n_mtiles) * 128;
  const int lr = tid >> 2, lc = (tid & 3) * 8;
  f32x4 acc[2][4] = {};
  const f16* Ap = A + (m0 + lr) * lda + lc;
  const f16* Bp = Bw + (n0 + lr) * ldb + lc;
  for (int k0 = 0; k0 < K; k0 += 32) {
    uint4 av = *(const uint4*)(Ap + k0);
    uint4 bv = *(const uint4*)(Bp + k0);
    __syncthreads();
    *(uint4*)&As[lr][lc] = av;
    *(uint4*)&Bs[lr][lc] = bv;
    __syncthreads();
#pragma unroll
    for (int mi = 0; mi < 2; ++mi) {
      f16x8 af = *(const f16x8*)&As[wm * 32 + mi * 16 + (lane & 15)][(lane >> 4) * 8];
#pragma unroll
      for (int ni = 0; ni < 4; ++ni) {
        f16x8 bf = *(const f16x8*)&Bs[wn * 64 + ni * 16 + (lane & 15)][(lane >> 4) * 8];
        acc[mi][ni] = __builtin_amdgcn_mfma_f32_16x16x32_f16(af, bf, acc[mi][ni], 0, 0, 0);
      }
    }
  }
#pragma unroll
  for (int mi = 0; mi < 2; ++mi)
#pragma unroll
    for (int ni = 0; ni < 4; ++ni) {
      int row_b = wm * 32 + mi * 16 + (lane >> 4) * 4;
      long gcol = n0 + wn * 64 + ni * 16 + (lane & 15);
      float badd = (bias1 ? bias1[gcol] : 0.f) + (bias2 ? bias2[gcol] : 0.f);
#pragma unroll
      for (int r = 0; r < 4; ++r) {
        long grow = m0 + row_b + r;
        Cout[grow * ldc + gcol] = acc[mi][ni][r] + badd;
      }
    }
}

// ---------------- persistent fused recurrence: 40 GEMM blocks + 64 step blocks --------------
// Per-slot flag signaling (plain sc stores, distinct addresses) + per-lane vector polling.
// flagR[t*64+j] (j<40): R cols ready. flagH[t*64+b] (b<64): h(t) ready.
__global__ __launch_bounds__(512, 1) void k_loop3(
    const f16* __restrict__ Wcat, const float* __restrict__ b_Ua,
    const f16* __restrict__ att1, const float* __restrict__ va,
    const f16* __restrict__ featW4, const float* __restrict__ gates_x,
    const float* __restrict__ c_state, unsigned* __restrict__ h2,
    f16* __restrict__ Hbuf, float* __restrict__ attw_out,
    float* __restrict__ R, unsigned* __restrict__ flagR, unsigned* __restrict__ flagH) {
  const int blk = blockIdx.x, tid = threadIdx.x;
  const int lane = tid & 63, wave = tid >> 6;

  if (blk < 40) {
    // ---------- GEMM role: R[:, n0:n0+64] = h @ Wcat[n0:n0+64, :]^T ----------
    const int n0 = blk * 64;
    const int l15 = lane & 15;
    const int mrow = (wave & 3) * 16 + l15;            // h row (batch index)
    const int nb = n0 + (wave >> 2) * 32;
    const unsigned* hrow = h2 + mrow * 256 + (lane >> 4) * 4;
    const f16* B0 = Wcat + (long)(nb + l15) * 512 + (lane >> 4) * 8;
    const f16* B1 = Wcat + (long)(nb + 16 + l15) * 512 + (lane >> 4) * 8;
    const int r0 = (wave & 3) * 16 + (lane >> 4) * 4;
    const int col0 = nb + l15;
    for (int t = 0; t < 32; ++t) {
      if (t > 0) {
        if (wave == 0) {                   // lane b polls step-block b's flag for h(t-1)
          const unsigned* fh = flagH + (t - 1) * 64 + lane;
          while (ldau(fh) == 0) __builtin_amdgcn_s_sleep(1);
        }
        __syncthreads();
      }
      f32x4 acc0 = {}, acc1 = {};
#pragma unroll
      for (int k0 = 0; k0 < 16; ++k0) {
        uint4 au;
        au.x = ldau(hrow + k0 * 16 + 0);
        au.y = ldau(hrow + k0 * 16 + 1);
        au.z = ldau(hrow + k0 * 16 + 2);
        au.w = ldau(hrow + k0 * 16 + 3);
        f16x8 af = __builtin_bit_cast(f16x8, au);
        f16x8 bf0 = *(const f16x8*)(B0 + k0 * 32);
        f16x8 bf1 = *(const f16x8*)(B1 + k0 * 32);
        acc0 = __builtin_amdgcn_mfma_f32_16x16x32_f16(af, bf0, acc0, 0, 0, 0);
        acc1 = __builtin_amdgcn_mfma_f32_16x16x32_f16(af, bf1, acc1, 0, 0, 0);
      }
#pragma unroll
      for (int r = 0; r < 4; ++r) {
        staf(&R[(long)(r0 + r) * 2560 + col0], acc0[r]);
        staf(&R[(long)(r0 + r) * 2560 + col0 + 16], acc1[r]);
      }
      asm volatile("s_waitcnt vmcnt(0)" ::: "memory");
      __syncthreads();                                  // all waves' R stores at LLC
      if (tid == 0) stau(&flagR[t * 64 + blk], 1u);
    }
  } else {
    // ---------- step role: batch b = blk-40 ----------
    __shared__ float att2[512];
    __shared__ float sc[64];
    __shared__ float wl[49];
    const int b = blk - 40;
    float c = c_state[(long)b * 512 + tid];
    const float bua_r = b_Ua[tid];
    float va_r[8];
#pragma unroll
    for (int kk = 0; kk < 8; ++kk) va_r[kk] = va[lane + kk * 64];
    const f16* fwbase = featW4 + (long)b * 49 * 2048 + tid * 4;
    const float* Rb = R + (long)b * 2560;

    for (int t = 0; t < 32; ++t) {
      const long n = (long)b * 32 + t;
      const float* gx = gates_x + n * 2048;

      // t-constant prefetches: issue BEFORE the rendezvous (hidden under polling)
      uint2 fw[49];
#pragma unroll
      for (int p = 0; p < 49; ++p) fw[p] = *(const uint2*)(fwbase + (long)p * 2048);
      float g0 = gx[tid], g1 = gx[512 + tid], g2 = gx[1024 + tid], g3 = gx[1536 + tid];

      // rendezvous: wave 0, lane j<40 spins on flagR[t*64+j]
      if (wave == 0 && lane < 40) {
        const unsigned* fr = flagR + t * 64 + lane;
        while (ldau(fr) == 0) __builtin_amdgcn_s_sleep(1);
      }
      __syncthreads();

      att2[tid] = ldaf(Rb + 2048 + tid) + bua_r;
      g0 += ldaf(Rb + tid);
      g1 += ldaf(Rb + 512 + tid);
      g2 += ldaf(Rb + 1024 + tid);
      g3 += ldaf(Rb + 1536 + tid);
      __syncthreads();                                  // att2 ready

      for (int p = wave; p < 49; p += 8) {
        const f16* arow = att1 + ((long)b * 49 + p) * 512;
        float s = 0.f;
#pragma unroll
        for (int kk = 0; kk < 8; ++kk) {
          int k = lane + kk * 64;
          float x = (float)arow[k] + att2[k];
          float e = __expf(2.f * x);
          float th = 1.f - 2.f / (e + 1.f);
          s += va_r[kk] * th;
        }
#pragma unroll
        for (int off = 32; off; off >>= 1) s += __shfl_xor(s, off);
        if (lane == 0) sc[p] = s;
      }
      __syncthreads();

      if (wave == 0) {
        float s = (lane < 49) ? sc[lane] : -1e30f;
        float m = s;
#pragma unroll
        for (int off = 32; off; off >>= 1) m = fmaxf(m, __shfl_xor(m, off));
        float e = (lane < 49) ? __expf(s - m) : 0.f;
        float sum = e;
#pragma unroll
        for (int off = 32; off; off >>= 1) sum += __shfl_xor(sum, off);
        float wv = e / sum;
        if (lane < 49) { wl[lane] = wv; attw_out[n * 49 + lane] = wv; }
      }
      __syncthreads();

#pragma unroll
      for (int p = 0; p < 49; ++p) {
        float wp = wl[p];
        f16x2 aa = __builtin_bit_cast(f16x2, fw[p].x);
        f16x2 bb = __builtin_bit_cast(f16x2, fw[p].y);
        g0 += wp * (float)aa.x; g1 += wp * (float)aa.y;
        g2 += wp * (float)bb.x; g3 += wp * (float)bb.y;
      }
      float iv = 1.f / (1.f + __expf(-g0));
      float fv = 1.f / (1.f + __expf(-g1));
      float e2 = __expf(2.f * g2); float gv = 1.f - 2.f / (e2 + 1.f);
      float ov = 1.f / (1.f + __expf(-g3));
      c = fv * c + iv * gv;
      float e3 = __expf(2.f * c); float tc = 1.f - 2.f / (e3 + 1.f);
      float hn = ov * tc;

      unsigned hb = (unsigned)__builtin_bit_cast(unsigned short, (f16)hn);
      unsigned pr = __shfl_xor(hb, 1);
      if ((tid & 1) == 0) stau(&h2[(long)b * 256 + (tid >> 1)], hb | (pr << 16));
      Hbuf[n * 512 + tid] = (f16)hn;

      asm volatile("s_waitcnt vmcnt(0)" ::: "memory");
      __syncthreads();                                  // h2 stores at LLC
      if (tid == 0 && t < 31) stau(&flagH[t * 64 + b], 1u);
    }
  }
}

extern "C" void kernel_launch(void* const* d_in, const int* in_sizes, int n_in,
                              void* d_out, int out_size, void* d_ws, size_t ws_size,
                              hipStream_t stream) {
  const int*   caps = (const int*)d_in[0];
  const float* feat = (const float*)d_in[1];
  const float* etab = (const float*)d_in[2];
  const float* W_a  = (const float*)d_in[3];
  const float* b_Wa = (const float*)d_in[4];
  const float* U_a  = (const float*)d_in[5];
  const float* b_Ua = (const float*)d_in[6];
  const float* v_a  = (const float*)d_in[7];
  /* d_in[8] b_va: softmax-invariant, unused */
  const float* W_ih = (const float*)d_in[9];
  const float* b_ih = (const float*)d_in[10];
  const float* W_hh = (const float*)d_in[11];
  const float* b_hh = (const float*)d_in[12];
  const float* fc_W = (const float*)d_in[13];
  const float* fc_b = (const float*)d_in[14];
  const float* Wh   = (const float*)d_in[15];
  const float* bh   = (const float*)d_in[16];
  const float* Wc   = (const float*)d_in[17];
  const float* bc   = (const float*)d_in[18];

  char* ws = (char*)d_ws;
  size_t off = 0;
  auto alloc = [&](size_t bytes) { void* p = ws + off; off += (bytes + 255) & ~(size_t)255; return p; };
  f16* feat_h  = (f16*)alloc(6422528ull * 2);   // B*P*F
  f16* W_a_h   = (f16*)alloc(1048576ull * 2);   // H*F
  f16* W_ih_h  = (f16*)alloc(5242880ull * 2);   // 4H*(E+F)
  f16* fc_W_h  = (f16*)alloc(16384000ull * 2);  // V*H
  f16* Aemb    = (f16*)alloc(1048576ull * 2);   // B*S*E
  f16* Wcat_h  = (f16*)alloc(1310720ull * 2);   // [W_hh;U_a] = [2560,512] f16
  f16* Whc_h   = (f16*)alloc(2097152ull * 2);   // [Wh;Wc] = [1024,2048] f16
  f16* mean_h  = (f16*)alloc(131072ull * 2);    // [64,2048] mean features f16
  f16* att1_h  = (f16*)alloc(1605632ull * 2);   // B*P*H
  f16* featW4  = (f16*)alloc(6422528ull * 2);   // B*P*4H interleaved
  float* gates_x = (float*)alloc(4194304ull * 4); // B*S*4H
  float* R     = (float*)alloc(163840ull * 4);  // [64,2560] per-step GEMM out (also h0/c0 out)
  unsigned* h2 = (unsigned*)alloc(16384ull * 4);// [64,256] packed f16x2 h state
  float* c_state = (float*)alloc(32768ull * 4); // [64,512] c state
  f16* Hbuf    = (f16*)alloc(1048576ull * 2);   // B*S*H
  unsigned* flags = (unsigned*)alloc(16384);    // flagR[32][64] + flagH[32][64]
  (void)ws_size; (void)in_sizes; (void)n_in; (void)out_size;
  unsigned* flagR = flags;
  unsigned* flagH = flags + 2048;

  float* out_logits = (float*)d_out;
  float* out_attw   = out_logits + 65536000ull;

  // Phase A: fused converts + gathers + precompute
  hipMemsetAsync(flags, 0, 16384, stream);
  k_prep<<<4096, 256, 0, stream>>>(feat, W_a, W_ih, fc_W, W_hh, U_a, Wh, Wc,
                                   feat_h, W_a_h, W_ih_h, fc_W_h, Wcat_h, Whc_h);
  k_embed<<<2048, 256, 0, stream>>>(caps, etab, Aemb);
  k_mean<<<dim3(64, 2), 256, 0, stream>>>(feat_h, mean_h);

  dim3 blk(256);
  // h0/c0: [64,1024] = mean_h @ [Wh;Wc]^T  K=2048 -> f32 (biases added in split)
  k_gemm<<<16, blk, 0, stream>>>(mean_h, 2048, Whc_h, 2048,
                                 nullptr, nullptr, R, 1024, 2048, 0, 1);
  k_h0split<<<64, 512, 0, stream>>>(R, bh, bc, h2, c_state);

  // att1 = features @ W_a^T + b_Wa         [3136,512]  K=2048 -> f16   (49 m x 8 n)
  k_gemm<<<49 * 8, blk, 0, stream>>>(feat_h, 2048, W_a_h, 2048,
                                     b_Wa, nullptr, att1_h, 512, 2048, 1, 49);
  // featW = features @ W_ih[:,E:]^T        [3136,2048] K=2048 -> f16 g-interleaved (49 x 32)
  k_gemm<<<49 * 32, blk, 0, stream>>>(feat_h, 2048, W_ih_h + 512, 2560,
                                      nullptr, nullptr, featW4, 0, 2048, 2, 49);
  // gates_x = embed @ W_ih[:,:E]^T + b_ih + b_hh   [2048,2048] K=512 -> f32 (16 x 16 @128)
  k_gemm128<<<16 * 16, 512, 0, stream>>>(Aemb, 512, W_ih_h, 2560,
                                         b_ih, b_hh, gates_x, 2048, 512, 16);

  // Phase B: persistent fused recurrence (40 GEMM blocks + 64 step blocks, flag rendezvous)
  k_loop3<<<104, 512, 0, stream>>>(Wcat_h, b_Ua, att1_h, v_a, featW4, gates_x,
                                   c_state, h2, Hbuf, out_attw, R, flagR, flagH);

  // Phase C: logits = H @ fc_W^T + fc_b    [2048,32000] K=512 -> f32 (16 m x 250 n @128)
  k_gemm128<<<16 * 250, 512, 0, stream>>>(Hbuf, 512, fc_W_h, 512,
                                          fc_b, nullptr, out_logits, 32000, 512, 16);
}

// Round 8
// 983.362 us; speedup vs baseline: 1.4187x; 1.4187x over previous
//
#include <hip/hip_runtime.h>
#include <hip/hip_fp16.h>

typedef _Float16 f16;
typedef _Float16 f16x2 __attribute__((ext_vector_type(2)));
typedef _Float16 f16x4 __attribute__((ext_vector_type(4)));
typedef _Float16 f16x8 __attribute__((ext_vector_type(8)));
typedef float    f32x4 __attribute__((ext_vector_type(4)));

// Problem constants: B=64, S=32, P=49, F=2048, E=512, H=512, V=32000
// M=3136 (B*P) padded to 3200 for 128-row tiles.

#define GLD16(g, l)                                                        \
  __builtin_amdgcn_global_load_lds(                                        \
      (const __attribute__((address_space(1))) void*)(g),                  \
      (__attribute__((address_space(3))) void*)(l), 16, 0, 0)

// ---------------- fused f32->f16 converts + embedding gather (ONE dispatch) ----------------
__global__ __launch_bounds__(256) void k_prep(
    const float* __restrict__ feat, const float* __restrict__ W_a,
    const float* __restrict__ W_ih, const float* __restrict__ fc_W,
    const float* __restrict__ W_hh, const float* __restrict__ U_a,
    const float* __restrict__ Wh, const float* __restrict__ Wc,
    const int* __restrict__ caps, const float* __restrict__ etab,
    f16* __restrict__ feat_h, f16* __restrict__ W_a_h,
    f16* __restrict__ W_ih_h, f16* __restrict__ fc_W_h,
    f16* __restrict__ Wcat_h, f16* __restrict__ Whc_h, f16* __restrict__ Aemb) {
  const long c0 = 1605632;              // feat      (6422528 f32 /4)
  const long c1 = c0 + 262144;          // W_a       (1048576)
  const long c2 = c1 + 1310720;         // W_ih      (5242880)
  const long c3 = c2 + 4096000;         // fc_W      (16384000)
  const long c4 = c3 + 262144;          // W_hh -> Wcat rows 0..2047
  const long c5 = c4 + 65536;           // U_a  -> Wcat rows 2048..2559
  const long c6 = c5 + 262144;          // Wh   -> Whc rows 0..511
  const long c7 = c6 + 262144;          // Wc   -> Whc rows 512..1023
  const long c8 = c7 + 262144;          // embed: 2048 rows x 128 f16x4 chunks
  long i = (long)blockIdx.x * 256 + threadIdx.x;
  const long stride = (long)gridDim.x * 256;
  for (; i < c8; i += stride) {
    const float4* s; f16x4* d; long j;
    if (i < c0)      { s = (const float4*)feat; d = (f16x4*)feat_h; j = i; }
    else if (i < c1) { s = (const float4*)W_a;  d = (f16x4*)W_a_h;  j = i - c0; }
    else if (i < c2) { s = (const float4*)W_ih; d = (f16x4*)W_ih_h; j = i - c1; }
    else if (i < c3) { s = (const float4*)fc_W; d = (f16x4*)fc_W_h; j = i - c2; }
    else if (i < c4) { s = (const float4*)W_hh; d = (f16x4*)Wcat_h; j = i - c3; }
    else if (i < c5) { s = (const float4*)U_a;  d = (f16x4*)(Wcat_h + 2048l * 512); j = i - c4; }
    else if (i < c6) { s = (const float4*)Wh;   d = (f16x4*)Whc_h;  j = i - c5; }
    else if (i < c7) { s = (const float4*)Wc;   d = (f16x4*)(Whc_h + 1048576l); j = i - c6; }
    else {
      long jj = i - c7;                 // embedding gather region
      int n = (int)(jj >> 7), e4 = (int)(jj & 127);
      int tok = caps[n];
      s = (const float4*)(etab + (long)tok * 512); d = (f16x4*)(Aemb + (long)n * 512); j = e4;
    }
    float4 v = s[j];
    f16x4 o; o.x = (f16)v.x; o.y = (f16)v.y; o.z = (f16)v.z; o.w = (f16)v.w;
    d[j] = o;
  }
}

// ---------------- mean of features over P (from f16 feat) -> f16 [64,2048] ----------------
__global__ __launch_bounds__(256) void k_mean(const f16* __restrict__ feat_h,
                                              f16* __restrict__ mean_h) {
  int b = blockIdx.x;
  int e4 = blockIdx.y * 256 + threadIdx.x;      // f16x4 index within row: 0..511
  const f16x4* src = (const f16x4*)(feat_h + (long)b * 49 * 2048) + e4;
  float s0 = 0.f, s1 = 0.f, s2 = 0.f, s3 = 0.f;
#pragma unroll 7
  for (int p = 0; p < 49; ++p) {
    f16x4 v = src[p * 512];
    s0 += (float)v.x; s1 += (float)v.y; s2 += (float)v.z; s3 += (float)v.w;
  }
  const float inv = 1.f / 49.f;
  f16x4 o; o.x = (f16)(s0 * inv); o.y = (f16)(s1 * inv); o.z = (f16)(s2 * inv); o.w = (f16)(s3 * inv);
  ((f16x4*)(mean_h + (long)b * 2048))[e4] = o;
}

// ---------------- split h0/c0 GEMM result, add biases ----------------
__global__ __launch_bounds__(512) void k_h0split(const float* __restrict__ Rh0,
                                                 const float* __restrict__ bh,
                                                 const float* __restrict__ bc,
                                                 f16* __restrict__ h16,
                                                 float* __restrict__ c_state) {
  int b = blockIdx.x, j = threadIdx.x;
  h16[(long)b * 512 + j] = (f16)(Rh0[(long)b * 1024 + j] + bh[j]);
  c_state[(long)b * 512 + j] = Rh0[(long)b * 1024 + 512 + j] + bc[j];
}

// ---------------- generic f16 MFMA GEMM (64x64 tile) — used only for h0/c0 (M=64) ----------
__global__ __launch_bounds__(256) void k_gemm(const f16* __restrict__ A, long lda,
                                              const f16* __restrict__ Bw, long ldb,
                                              const float* __restrict__ bias1,
                                              const float* __restrict__ bias2,
                                              void* __restrict__ Cout, long ldc,
                                              int K, int mode, int n_mtiles) {
  __shared__ f16 As[64][40];
  __shared__ f16 Bs[64][40];
  const int tid = threadIdx.x;
  const int lane = tid & 63, wave = tid >> 6;
  const int bid = blockIdx.x;
  const long m0 = (long)(bid % n_mtiles) * 64, n0 = (long)(bid / n_mtiles) * 64;
  const int lr = tid >> 2, lc = (tid & 3) * 8;
  const int wr = (wave >> 1) * 32, wc = (wave & 1) * 32;
  f32x4 acc[2][2] = {};
  const f16* Ap = A + (m0 + lr) * lda + lc;
  const f16* Bp = Bw + (n0 + lr) * ldb + lc;
  for (int k0 = 0; k0 < K; k0 += 32) {
    uint4 av = *(const uint4*)(Ap + k0);
    uint4 bv = *(const uint4*)(Bp + k0);
    __syncthreads();
    *(uint4*)&As[lr][lc] = av;
    *(uint4*)&Bs[lr][lc] = bv;
    __syncthreads();
#pragma unroll
    for (int mi = 0; mi < 2; ++mi) {
      f16x8 af = *(const f16x8*)&As[wr + mi * 16 + (lane & 15)][(lane >> 4) * 8];
#pragma unroll
      for (int ni = 0; ni < 2; ++ni) {
        f16x8 bf = *(const f16x8*)&Bs[wc + ni * 16 + (lane & 15)][(lane >> 4) * 8];
        acc[mi][ni] = __builtin_amdgcn_mfma_f32_16x16x32_f16(af, bf, acc[mi][ni], 0, 0, 0);
      }
    }
  }
#pragma unroll
  for (int mi = 0; mi < 2; ++mi)
#pragma unroll
    for (int ni = 0; ni < 2; ++ni) {
      int row_b = wr + mi * 16 + (lane >> 4) * 4;
      long gcol = n0 + wc + ni * 16 + (lane & 15);
      float badd = (bias1 ? bias1[gcol] : 0.f) + (bias2 ? bias2[gcol] : 0.f);
#pragma unroll
      for (int r = 0; r < 4; ++r) {
        long grow = m0 + row_b + r;
        float v = acc[mi][ni][r] + badd;
        if (mode == 0)      ((float*)Cout)[grow * ldc + gcol] = v;
        else                ((f16*)Cout)[grow * ldc + gcol] = (f16)v;
      }
    }
}

// ---------------- 128x128 tile, BK=64, global_load_lds staging, XOR-swizzled LDS ------------
// C[M,N] = A[M,K] @ W[N,K]^T + bias. 512 threads / 8 waves (4m x 2n).
// LDS layout: linear [128 rows][8 slots of 16B]; slot phys = logical ^ (row&7).
// Staged via global_load_lds (lane-linear dest) from pre-swizzled global source.
// mode 0: f32 out @ ldc ; mode 1: f16 out @ ldc ; mode 2: f16 g-interleaved (featW4)
__global__ __launch_bounds__(512) void k_gemm128b(const f16* __restrict__ A, long lda,
                                                  const f16* __restrict__ Bw, long ldb,
                                                  const float* __restrict__ bias1,
                                                  const float* __restrict__ bias2,
                                                  void* __restrict__ Cout, long ldc,
                                                  int K, int mode, int n_mtiles) {
  __shared__ f16 As[8192];   // [128][64] = 16 KB
  __shared__ f16 Bs[8192];
  const int tid = threadIdx.x, lane = tid & 63, wave = tid >> 6;
  const int wm = wave & 3, wn = wave >> 2;
  const int bid = blockIdx.x;
  const long m0 = (long)(bid % n_mtiles) * 128, n0 = (long)(bid / n_mtiles) * 128;
  // staging chunks: c0 = wave*128+lane, c1 = c0+64 (16B chunks; 1024 per matrix)
  const int c0 = wave * 128 + lane, c1 = c0 + 64;
  const int r0 = c0 >> 3, s0 = (c0 & 7) ^ (r0 & 7);
  const int r1 = c1 >> 3, s1 = (c1 & 7) ^ (r1 & 7);
  const f16* gA0 = A + (m0 + r0) * lda + s0 * 8;
  const f16* gA1 = A + (m0 + r1) * lda + s1 * 8;
  const f16* gB0 = Bw + (n0 + r0) * ldb + s0 * 8;
  const f16* gB1 = Bw + (n0 + r1) * ldb + s1 * 8;
  f16* lA0 = As + (wave * 128) * 8;          // wave-uniform LDS bases (lane*16 added by HW)
  f16* lA1 = As + (wave * 128 + 64) * 8;
  f16* lB0 = Bs + (wave * 128) * 8;
  f16* lB1 = Bs + (wave * 128 + 64) * 8;
  f32x4 acc[2][4] = {};
  for (int k0 = 0; k0 < K; k0 += 64) {
    GLD16(gA0 + k0, lA0); GLD16(gA1 + k0, lA1);
    GLD16(gB0 + k0, lB0); GLD16(gB1 + k0, lB1);
    __syncthreads();                          // compiler drains vmcnt before s_barrier
#pragma unroll
    for (int ks = 0; ks < 2; ++ks) {
      const int sp = (ks * 4 + (lane >> 4)) ^ (lane & 7);   // phys slot for this lane
#pragma unroll
      for (int mi = 0; mi < 2; ++mi) {
        const int rA = wm * 32 + mi * 16 + (lane & 15);
        f16x8 af = *(const f16x8*)(As + rA * 64 + sp * 8);
#pragma unroll
        for (int ni = 0; ni < 4; ++ni) {
          const int rB = wn * 64 + ni * 16 + (lane & 15);
          f16x8 bf = *(const f16x8*)(Bs + rB * 64 + sp * 8);
          acc[mi][ni] = __builtin_amdgcn_mfma_f32_16x16x32_f16(af, bf, acc[mi][ni], 0, 0, 0);
        }
      }
    }
    __syncthreads();
  }
#pragma unroll
  for (int mi = 0; mi < 2; ++mi)
#pragma unroll
    for (int ni = 0; ni < 4; ++ni) {
      int row_b = wm * 32 + mi * 16 + (lane >> 4) * 4;
      long gcol = n0 + wn * 64 + ni * 16 + (lane & 15);
      float badd = (bias1 ? bias1[gcol] : 0.f) + (bias2 ? bias2[gcol] : 0.f);
#pragma unroll
      for (int r = 0; r < 4; ++r) {
        long grow = m0 + row_b + r;
        float v = acc[mi][ni][r] + badd;
        if (mode == 0)      ((float*)Cout)[grow * ldc + gcol] = v;
        else if (mode == 1) ((f16*)Cout)[grow * ldc + gcol] = (f16)v;
        else                ((f16*)Cout)[grow * 2048 + ((gcol & 511) << 2) + (gcol >> 9)] = (f16)v;
      }
    }
}

// ---------------- per-step R = h @ [W_hh;U_a]^T — register-direct MFMA, no LDS/barriers ----
__global__ __launch_bounds__(256) void k_rgemm(const f16* __restrict__ h16,
                                               const f16* __restrict__ Wcat,
                                               float* __restrict__ R) {
  const int tid = threadIdx.x, lane = tid & 63, wave = tid >> 6;
  const int n0 = blockIdx.x * 64;
  const int l15 = lane & 15;
  const int koff = (lane >> 4) * 8;
  f32x4 acc[4] = {};
  const f16* Ap = h16 + ((long)(wave * 16 + l15) << 9) + koff;
#pragma unroll
  for (int k0 = 0; k0 < 16; ++k0) {
    f16x8 af = *(const f16x8*)(Ap + k0 * 32);
#pragma unroll
    for (int ni = 0; ni < 4; ++ni) {
      f16x8 bf = *(const f16x8*)(Wcat + ((long)(n0 + ni * 16 + l15) << 9) + koff + k0 * 32);
      acc[ni] = __builtin_amdgcn_mfma_f32_16x16x32_f16(af, bf, acc[ni], 0, 0, 0);
    }
  }
  const int r0 = wave * 16 + (lane >> 4) * 4;
#pragma unroll
  for (int ni = 0; ni < 4; ++ni) {
    int col = n0 + ni * 16 + l15;
#pragma unroll
    for (int r = 0; r < 4; ++r)
      R[(long)(r0 + r) * 2560 + col] = acc[ni][r];
  }
}

// ---------------- per-step: attention + softmax + ctx + LSTM pointwise ----------------
__global__ __launch_bounds__(512) void k_step(const float* __restrict__ R,
                                              const float* __restrict__ b_Ua,
                                              const f16* __restrict__ att1,
                                              const float* __restrict__ va,
                                              const f16* __restrict__ featW4,
                                              const float* __restrict__ gates_x,
                                              float* __restrict__ c_state,
                                              f16* __restrict__ h16,
                                              f16* __restrict__ Hbuf,
                                              float* __restrict__ attw_out,
                                              int t) {
  __shared__ float att2[512];
  __shared__ float sc[64];
  __shared__ float wl[49];
  const int b = blockIdx.x, tid = threadIdx.x;
  const int lane = tid & 63, wave = tid >> 6;
  const long n = (long)b * 32 + t;
  const float* Rb = R + (long)b * 2560;
  const float* gx = gates_x + n * 2048;

  float g0 = gx[tid] + Rb[tid];
  float g1 = gx[512 + tid] + Rb[512 + tid];
  float g2 = gx[1024 + tid] + Rb[1024 + tid];
  float g3 = gx[1536 + tid] + Rb[1536 + tid];
  float c = c_state[(long)b * 512 + tid];

  att2[tid] = Rb[2048 + tid] + b_Ua[tid];
  __syncthreads();

  for (int p = wave; p < 49; p += 8) {
    const f16* arow = att1 + ((long)b * 49 + p) * 512;
    float s = 0.f;
#pragma unroll
    for (int kk = 0; kk < 8; ++kk) {
      int k = lane + kk * 64;
      float x = (float)arow[k] + att2[k];
      float e = __expf(2.f * x);
      float th = 1.f - 2.f / (e + 1.f);
      s += va[k] * th;
    }
#pragma unroll
    for (int off = 32; off; off >>= 1) s += __shfl_xor(s, off);
    if (lane == 0) sc[p] = s;
  }
  __syncthreads();

  if (wave == 0) {
    float s = (lane < 49) ? sc[lane] : -1e30f;
    float m = s;
#pragma unroll
    for (int off = 32; off; off >>= 1) m = fmaxf(m, __shfl_xor(m, off));
    float e = (lane < 49) ? __expf(s - m) : 0.f;
    float sum = e;
#pragma unroll
    for (int off = 32; off; off >>= 1) sum += __shfl_xor(sum, off);
    float wv = e / sum;
    if (lane < 49) { wl[lane] = wv; attw_out[n * 49 + lane] = wv; }
  }
  __syncthreads();

  const f16* fwbase = featW4 + (long)b * 49 * 2048 + tid * 4;
#pragma unroll
  for (int p = 0; p < 49; ++p) {
    float wp = wl[p];
    uint2 u = *(const uint2*)(fwbase + (long)p * 2048);
    f16x2 aa = __builtin_bit_cast(f16x2, u.x);
    f16x2 bb = __builtin_bit_cast(f16x2, u.y);
    g0 += wp * (float)aa.x; g1 += wp * (float)aa.y;
    g2 += wp * (float)bb.x; g3 += wp * (float)bb.y;
  }
  float iv = 1.f / (1.f + __expf(-g0));
  float fv = 1.f / (1.f + __expf(-g1));
  float e2 = __expf(2.f * g2); float gv = 1.f - 2.f / (e2 + 1.f);
  float ov = 1.f / (1.f + __expf(-g3));
  c = fv * c + iv * gv;
  float e3 = __expf(2.f * c); float tc = 1.f - 2.f / (e3 + 1.f);
  float hn = ov * tc;
  c_state[(long)b * 512 + tid] = c;
  h16[(long)b * 512 + tid] = (f16)hn;
  Hbuf[n * 512 + tid] = (f16)hn;
}

extern "C" void kernel_launch(void* const* d_in, const int* in_sizes, int n_in,
                              void* d_out, int out_size, void* d_ws, size_t ws_size,
                              hipStream_t stream) {
  const int*   caps = (const int*)d_in[0];
  const float* feat = (const float*)d_in[1];
  const float* etab = (const float*)d_in[2];
  const float* W_a  = (const float*)d_in[3];
  const float* b_Wa = (const float*)d_in[4];
  const float* U_a  = (const float*)d_in[5];
  const float* b_Ua = (const float*)d_in[6];
  const float* v_a  = (const float*)d_in[7];
  /* d_in[8] b_va: softmax-invariant, unused */
  const float* W_ih = (const float*)d_in[9];
  const float* b_ih = (const float*)d_in[10];
  const float* W_hh = (const float*)d_in[11];
  const float* b_hh = (const float*)d_in[12];
  const float* fc_W = (const float*)d_in[13];
  const float* fc_b = (const float*)d_in[14];
  const float* Wh   = (const float*)d_in[15];
  const float* bh   = (const float*)d_in[16];
  const float* Wc   = (const float*)d_in[17];
  const float* bc   = (const float*)d_in[18];

  char* ws = (char*)d_ws;
  size_t off = 0;
  auto alloc = [&](size_t bytes) { void* p = ws + off; off += (bytes + 255) & ~(size_t)255; return p; };
  f16* feat_h  = (f16*)alloc(6553600ull * 2);   // [3200,2048] (3136 valid rows)
  f16* W_a_h   = (f16*)alloc(1048576ull * 2);   // H*F
  f16* W_ih_h  = (f16*)alloc(5242880ull * 2);   // 4H*(E+F)
  f16* fc_W_h  = (f16*)alloc(16384000ull * 2);  // V*H
  f16* Aemb    = (f16*)alloc(1048576ull * 2);   // B*S*E
  f16* Wcat_h  = (f16*)alloc(1310720ull * 2);   // [W_hh;U_a] = [2560,512] f16
  f16* Whc_h   = (f16*)alloc(2097152ull * 2);   // [Wh;Wc] = [1024,2048] f16
  f16* mean_h  = (f16*)alloc(131072ull * 2);    // [64,2048] mean features f16
  f16* att1_h  = (f16*)alloc(1638400ull * 2);   // [3200,512] (3136 valid)
  f16* featW4  = (f16*)alloc(6553600ull * 2);   // [3200,2048] g-interleaved (3136 valid)
  float* gates_x = (float*)alloc(4194304ull * 4); // B*S*4H
  float* R     = (float*)alloc(163840ull * 4);  // [64,2560] per-step GEMM out (also h0/c0 out)
  f16* h16     = (f16*)alloc(32768ull * 2);     // [64,512] h state
  float* c_state = (float*)alloc(32768ull * 4); // [64,512] c state
  f16* Hbuf    = (f16*)alloc(1048576ull * 2);   // B*S*H
  (void)ws_size; (void)in_sizes; (void)n_in; (void)out_size;

  float* out_logits = (float*)d_out;
  float* out_attw   = out_logits + 65536000ull;

  // Phase A: fused converts + embedding gather, then precompute
  k_prep<<<4096, 256, 0, stream>>>(feat, W_a, W_ih, fc_W, W_hh, U_a, Wh, Wc, caps, etab,
                                   feat_h, W_a_h, W_ih_h, fc_W_h, Wcat_h, Whc_h, Aemb);
  k_mean<<<dim3(64, 2), 256, 0, stream>>>(feat_h, mean_h);

  // h0/c0: [64,1024] = mean_h @ [Wh;Wc]^T  K=2048 -> f32 (biases added in split)
  k_gemm<<<16, 256, 0, stream>>>(mean_h, 2048, Whc_h, 2048,
                                 nullptr, nullptr, R, 1024, 2048, 0, 1);
  k_h0split<<<64, 512, 0, stream>>>(R, bh, bc, h16, c_state);

  // att1 = features @ W_a^T + b_Wa         [3200,512]  K=2048 -> f16   (25 m x 4 n)
  k_gemm128b<<<25 * 4, 512, 0, stream>>>(feat_h, 2048, W_a_h, 2048,
                                         b_Wa, nullptr, att1_h, 512, 2048, 1, 25);
  // featW = features @ W_ih[:,E:]^T        [3200,2048] K=2048 -> f16 g-interleaved (25 x 16)
  k_gemm128b<<<25 * 16, 512, 0, stream>>>(feat_h, 2048, W_ih_h + 512, 2560,
                                          nullptr, nullptr, featW4, 0, 2048, 2, 25);
  // gates_x = embed @ W_ih[:,:E]^T + b_ih + b_hh   [2048,2048] K=512 -> f32 (16 x 16)
  k_gemm128b<<<16 * 16, 512, 0, stream>>>(Aemb, 512, W_ih_h, 2560,
                                          b_ih, b_hh, gates_x, 2048, 512, 0, 16);

  // Phase B: sequential recurrence — per step: register-MFMA GEMM + fused step kernel
  for (int t = 0; t < 32; ++t) {
    k_rgemm<<<40, 256, 0, stream>>>(h16, Wcat_h, R);
    k_step<<<64, 512, 0, stream>>>(R, b_Ua, att1_h, v_a, featW4, gates_x,
                                   c_state, h16, Hbuf, out_attw, t);
  }

  // Phase C: logits = H @ fc_W^T + fc_b    [2048,32000] K=512 -> f32 (16 m x 250 n)
  k_gemm128b<<<16 * 250, 512, 0, stream>>>(Hbuf, 512, fc_W_h, 512,
                                           fc_b, nullptr, out_logits, 32000, 512, 0, 16);
}